// Round 9
// baseline (1413.900 us; speedup 1.0000x reference)
//
#include <hip/hip_runtime.h>
#include <stdint.h>
#include <stddef.h>

// ---------------------------------------------------------------------------
// MinGRU NLP model forward on MI355X (gfx950).  ALL float I/O is fp32.
// Pipeline: embed -> [LN -> gates GEMM -> scan(+res)] x3 -> LN -> vocab GEMM.
// Gates GEMMs: proven m97 128x128 2-phase structure (round-8 code).
// FINAL vocab GEMM: 256x256 8-phase template (T2+T3+T4+T5):
//   BK=64, 8 waves, 128KiB dbuf LDS, per-phase {ds_read || stage -> barrier ->
//   setprio(1) 16xMFMA setprio(0) -> barrier}, counted vmcnt only at tile
//   swap, XOR-swizzled LDS via pre-swizzled global source (rule #21).
// Scan: 3-kernel chunked linear recurrence h = a*h + v (32 chunks x 64).
// ---------------------------------------------------------------------------

typedef __attribute__((ext_vector_type(4))) float f32x4;
typedef __attribute__((ext_vector_type(8))) short bf16x8;
typedef float f32x4u __attribute__((vector_size(16), aligned(4)));

__device__ __forceinline__ unsigned short f2bf(float f) {
  unsigned int u = __float_as_uint(f);
  u += 0x7FFFu + ((u >> 16) & 1u);  // RNE
  return (unsigned short)(u >> 16);
}

__device__ __forceinline__ void gload16(const void* g, void* l) {
  __builtin_amdgcn_global_load_lds(
      (const __attribute__((address_space(1))) void*)g,
      (__attribute__((address_space(3))) void*)l, 16, 0, 0);
}

#define MEMFENCE asm volatile("" ::: "memory")

// ---------------------------------------------------------------------------
// fp32 -> bf16 conversion, 8 elems/thread/iter, grid-stride.
__global__ __launch_bounds__(256) void cvt_kernel(
    const float* __restrict__ in, unsigned short* __restrict__ out, int n8) {
  int i = blockIdx.x * 256 + threadIdx.x;
  int stride = gridDim.x * 256;
  for (; i < n8; i += stride) {
    const float4* p = (const float4*)in + (size_t)i * 2;
    float4 a = p[0], b = p[1];
    bf16x8 o;
    o[0] = (short)f2bf(a.x); o[1] = (short)f2bf(a.y);
    o[2] = (short)f2bf(a.z); o[3] = (short)f2bf(a.w);
    o[4] = (short)f2bf(b.x); o[5] = (short)f2bf(b.y);
    o[6] = (short)f2bf(b.z); o[7] = (short)f2bf(b.w);
    *(bf16x8*)(out + (size_t)i * 8) = o;
  }
}

// ---------------------------------------------------------------------------
// Embedding gather + bf16 cast: x_bf[tok, 0:768] = bf16(embW[ids[tok], :])
__global__ __launch_bounds__(256) void embed_kernel(
    const int* __restrict__ ids, const float* __restrict__ embW,
    unsigned short* __restrict__ xbf) {
  int tok = blockIdx.x;
  int id = ids[tok];
  const float* src = embW + (size_t)id * 768;
  unsigned short* dst = xbf + (size_t)tok * 768;
  for (int j = threadIdx.x; j < 768; j += 256) dst[j] = f2bf(src[j]);
}

// ---------------------------------------------------------------------------
// LayerNorm over last dim D, one block per row. Output bf16.
template <int BF16IN, int D>
__global__ __launch_bounds__(256) void ln_kernel(
    const void* __restrict__ xin, const float* __restrict__ w,
    const float* __restrict__ b, unsigned short* __restrict__ xout,
    float eps) {
  constexpr int NV = D / 256;
  int row = blockIdx.x;
  int tid = threadIdx.x;
  int lane = tid & 63, wid = tid >> 6;
  const float* xf = (const float*)xin;
  const unsigned short* xb = (const unsigned short*)xin;
  float vals[NV];
  float s = 0.f, ss = 0.f;
#pragma unroll
  for (int i = 0; i < NV; i++) {
    size_t idx = (size_t)row * D + i * 256 + tid;
    float v;
    if (BF16IN) {
      unsigned int u = ((unsigned int)xb[idx]) << 16;
      v = __uint_as_float(u);
    } else {
      v = xf[idx];
    }
    vals[i] = v;
    s += v;
    ss += v * v;
  }
  for (int off = 32; off; off >>= 1) {
    s += __shfl_down(s, off);
    ss += __shfl_down(ss, off);
  }
  __shared__ float red[8];
  if (lane == 0) { red[wid] = s; red[4 + wid] = ss; }
  __syncthreads();
  s = red[0] + red[1] + red[2] + red[3];
  ss = red[4] + red[5] + red[6] + red[7];
  constexpr float invD = 1.f / (float)D;
  float mu = s * invD;
  float var = ss * invD - mu * mu;
  float inv = rsqrtf(var + eps);
#pragma unroll
  for (int i = 0; i < NV; i++) {
    int col = i * 256 + tid;
    size_t idx = (size_t)row * D + col;
    float y = (vals[i] - mu) * inv * w[col] + b[col];
    xout[idx] = f2bf(y);
  }
}

// ---------------------------------------------------------------------------
// 128x128 2-phase GEMM (round-8 proven) for the gates/res GEMMs.
// C[M,N] = A[M,K]*B[N,K]^T, fp32 out. Grid dim3(ncb, nrb), x fastest.
__global__ __launch_bounds__(256) void gemm_bt(
    const unsigned short* __restrict__ A, const unsigned short* __restrict__ B,
    float* __restrict__ C, int M, int N, int K) {
  __shared__ __align__(16) char smem[16896];
  unsigned short* lsA = (unsigned short*)smem;
  unsigned short* lsB = (unsigned short*)(smem + 8192);
  float* lsC = (float*)smem;

  const int tid = threadIdx.x;
  const int lane = tid & 63;
  const int wid = __builtin_amdgcn_readfirstlane(tid >> 6);
  const int row0 = blockIdx.y * 128;
  const int col0 = blockIdx.x * 128;

  const int srow = tid >> 2;
  const int skg = (tid & 3) * 8;

  const unsigned short* gA0 = A + (size_t)(row0 + srow) * K + skg;
  const unsigned short* gA1 = A + (size_t)(row0 + 64 + srow) * K + skg;
  const unsigned short* gB0 = B + (size_t)(col0 + srow) * K + skg;
  const unsigned short* gB1 = B + (size_t)(col0 + 64 + srow) * K + skg;

  char* ldsA0 = (char*)lsA + wid * 1024;
  char* ldsA1 = (char*)lsA + 4096 + wid * 1024;
  char* ldsB0 = (char*)lsB + wid * 1024;
  char* ldsB1 = (char*)lsB + 4096 + wid * 1024;

  const int wm = wid >> 1, wn = wid & 1;
  const unsigned short* pA = lsA + (wm * 64 + (lane & 15)) * 32 + (lane >> 4) * 8;
  const unsigned short* pB = lsB + (wn * 64 + (lane & 15)) * 32 + (lane >> 4) * 8;

  f32x4 acc[4][4] = {};

  for (int k0 = 0; k0 < K; k0 += 32) {
    gload16(gA0 + k0, ldsA0);
    gload16(gA1 + k0, ldsA1);
    gload16(gB0 + k0, ldsB0);
    gload16(gB1 + k0, ldsB1);
    __syncthreads();
    bf16x8 af[4], bfr[4];
#pragma unroll
    for (int i = 0; i < 4; i++) af[i] = *(const bf16x8*)(pA + i * 512);
#pragma unroll
    for (int i = 0; i < 4; i++) bfr[i] = *(const bf16x8*)(pB + i * 512);
#pragma unroll
    for (int i = 0; i < 4; i++)
#pragma unroll
      for (int j = 0; j < 4; j++)
        acc[i][j] = __builtin_amdgcn_mfma_f32_16x16x32_bf16(bfr[j], af[i],
                                                            acc[i][j], 0, 0, 0);
    __syncthreads();
  }

  const int mloc = lane & 15;
  const int ng = (lane >> 4) * 4;
  const int LDC = 132;
  const int trow = tid >> 5;
  const int tcol = (tid & 31) * 4;
#pragma unroll
  for (int c = 0; c < 4; c++) {
    if (wm == (c >> 1)) {
      const int i0 = 2 * (c & 1);
#pragma unroll
      for (int ii = 0; ii < 2; ii++)
#pragma unroll
        for (int j = 0; j < 4; j++)
          *(f32x4*)(lsC + (ii * 16 + mloc) * LDC + wn * 64 + j * 16 + ng) =
              acc[i0 + ii][j];
    }
    __syncthreads();
#pragma unroll
    for (int rr = 0; rr < 4; rr++) {
      const int r = rr * 8 + trow;
      const size_t gr = row0 + c * 32 + r;
      f32x4 v = *(const f32x4*)(lsC + r * LDC + tcol);
      *(f32x4*)(C + gr * N + col0 + tcol) = v;
    }
    __syncthreads();
  }
}

// ---------------------------------------------------------------------------
// 256x256 8-phase GEMM for the final vocab projection.
// C[M,N] = A[M,K]*B[N,K]^T + bias, fp32 nt out. K multiple of 64, M of 256.
// Grid dim3(M/256, ceil(N/256)), x (rows) fastest for L2/L3 B residency.
// LDS [256][64] bf16 per matrix, double-buffered (128 KiB). Swizzle: LDS
// slot (row, g) holds global granule g^(row&7); staged by pre-swizzling the
// GLOBAL source granule (linear gload_lds dest), read back with same XOR.
__global__ __launch_bounds__(512, 2) void gemm_bt256(
    const unsigned short* __restrict__ A, const unsigned short* __restrict__ B,
    float* __restrict__ C, const float* __restrict__ bias, int M, int N,
    int K) {
  __shared__ __align__(16) char smem[131072];
  char* const aBuf0 = smem;            // [2][256][64] bf16 (32768 B per buf)
  char* const bBuf0 = smem + 65536;

  const int t = threadIdx.x;
  const int l = t & 63;
  const int w = __builtin_amdgcn_readfirstlane(t >> 6);  // wave 0..7
  const int wm = w >> 2, wn = w & 3;                     // 2 x 4 wave grid
  const int row0 = blockIdx.x * 256;
  const int col0 = blockIdx.y * 256;

  // ---- staging addresses (pass i covers rows i*64 + t>>3, granule t&7) ----
  const int srow = t >> 3;                       // 0..63
  const int sg = ((t & 7) ^ (srow & 7)) * 8;     // pre-swizzled global granule
  const unsigned short* aS0 = A + (size_t)(row0 + srow) * K + sg;
  const unsigned short* aS1 = A + (size_t)(row0 + 64 + srow) * K + sg;
  const unsigned short* aS2 = A + (size_t)(row0 + 128 + srow) * K + sg;
  const unsigned short* aS3 = A + (size_t)(row0 + 192 + srow) * K + sg;
  int br0 = min(col0 + srow, N - 1);
  int br1 = min(col0 + 64 + srow, N - 1);
  int br2 = min(col0 + 128 + srow, N - 1);
  int br3 = min(col0 + 192 + srow, N - 1);
  const unsigned short* bS0 = B + (size_t)br0 * K + sg;
  const unsigned short* bS1 = B + (size_t)br1 * K + sg;
  const unsigned short* bS2 = B + (size_t)br2 * K + sg;
  const unsigned short* bS3 = B + (size_t)br3 * K + sg;
  const int wOff = w * 1024;  // wave-uniform LDS chunk within a pass

  // ---- fragment read addresses (byte offsets within a buffer) ----
  const int aRowB = (wm * 128 + (l & 15)) * 128;
  const int bRowB = (wn * 64 + (l & 15)) * 128;
  const int gK0 = (((l >> 4)) ^ (l & 7)) * 16;      // ks=0 granule, swizzled
  const int gK1 = ((4 + (l >> 4)) ^ (l & 7)) * 16;  // ks=1

  f32x4 acc[8][4] = {};

  // ---- prologue: stage K-tile 0 into buf 0 ----
  gload16(aS0, aBuf0 + wOff);
  gload16(aS1, aBuf0 + 8192 + wOff);
  gload16(aS2, aBuf0 + 16384 + wOff);
  gload16(aS3, aBuf0 + 24576 + wOff);
  gload16(bS0, bBuf0 + wOff);
  gload16(bS1, bBuf0 + 8192 + wOff);
  gload16(bS2, bBuf0 + 16384 + wOff);
  gload16(bS3, bBuf0 + 24576 + wOff);
  asm volatile("s_waitcnt vmcnt(0)" ::: "memory");
  __builtin_amdgcn_s_barrier();
  MEMFENCE;

  const int NT = K >> 6;
  int cur = 0;
  for (int kt = 0; kt < NT; ++kt) {
    const int nxt = cur ^ 1;
    const bool pre = (kt + 1 < NT);
    const int kN = (kt + 1) << 6;  // element offset of next K-tile
    const char* aB = aBuf0 + cur * 32768;
    const char* bB = bBuf0 + cur * 32768;
    char* aN = aBuf0 + nxt * 32768;
    char* bN = bBuf0 + nxt * 32768;

    bf16x8 bf[4][2];
    bf16x8 af[2][2];

#define LOAD_A(FR0)                                                    \
  af[0][0] = *(const bf16x8*)(aB + aRowB + (FR0) * 2048 + gK0);        \
  af[0][1] = *(const bf16x8*)(aB + aRowB + (FR0) * 2048 + gK1);        \
  af[1][0] = *(const bf16x8*)(aB + aRowB + ((FR0) + 1) * 2048 + gK0);  \
  af[1][1] = *(const bf16x8*)(aB + aRowB + ((FR0) + 1) * 2048 + gK1);

#define MFMA_PH(FR0)                                                      \
  __builtin_amdgcn_s_setprio(1);                                          \
  _Pragma("unroll") for (int ii = 0; ii < 2; ++ii) {                      \
    _Pragma("unroll") for (int fc = 0; fc < 4; ++fc) {                    \
      acc[(FR0) + ii][fc] = __builtin_amdgcn_mfma_f32_16x16x32_bf16(      \
          bf[fc][0], af[ii][0], acc[(FR0) + ii][fc], 0, 0, 0);            \
      acc[(FR0) + ii][fc] = __builtin_amdgcn_mfma_f32_16x16x32_bf16(      \
          bf[fc][1], af[ii][1], acc[(FR0) + ii][fc], 0, 0, 0);            \
    }                                                                     \
  }                                                                       \
  __builtin_amdgcn_s_setprio(0);

#define BARRIER_ \
  MEMFENCE;      \
  __builtin_amdgcn_s_barrier(); \
  MEMFENCE;

    // ---- phase 0: B frags + A rows 0-1; stage A passes 0-2 ----
#pragma unroll
    for (int fc = 0; fc < 4; ++fc) {
      bf[fc][0] = *(const bf16x8*)(bB + bRowB + fc * 2048 + gK0);
      bf[fc][1] = *(const bf16x8*)(bB + bRowB + fc * 2048 + gK1);
    }
    LOAD_A(0);
    if (pre) {
      gload16(aS0 + kN, aN + wOff);
      gload16(aS1 + kN, aN + 8192 + wOff);
      gload16(aS2 + kN, aN + 16384 + wOff);
    }
    BARRIER_;
    MFMA_PH(0);
    BARRIER_;

    // ---- phase 1: A rows 2-3; stage A pass 3, B passes 0-1 ----
    LOAD_A(2);
    if (pre) {
      gload16(aS3 + kN, aN + 24576 + wOff);
      gload16(bS0 + kN, bN + wOff);
      gload16(bS1 + kN, bN + 8192 + wOff);
    }
    BARRIER_;
    MFMA_PH(2);
    BARRIER_;

    // ---- phase 2: A rows 4-5; stage B passes 2-3 ----
    LOAD_A(4);
    if (pre) {
      gload16(bS2 + kN, bN + 16384 + wOff);
      gload16(bS3 + kN, bN + 24576 + wOff);
    }
    BARRIER_;
    MFMA_PH(4);
    BARRIER_;

    // ---- phase 3: A rows 6-7; no staging; tile-swap wait at end ----
    LOAD_A(6);
    BARRIER_;
    MFMA_PH(6);
    if (pre) asm volatile("s_waitcnt vmcnt(0)" ::: "memory");
    BARRIER_;

    cur = nxt;
#undef LOAD_A
#undef MFMA_PH
#undef BARRIER_
  }

  // ---- epilogue: direct nt stores (swapped-operand layout) ----
  const int mB = row0 + wm * 128 + (l & 15);
  const int nB = col0 + wn * 64 + ((l >> 4) << 2);
#pragma unroll
  for (int fr = 0; fr < 8; ++fr) {
    const size_t mRow = (size_t)(mB + fr * 16) * N;
#pragma unroll
    for (int fc = 0; fc < 4; ++fc) {
      const int n0 = nB + fc * 16;
      f32x4 v = acc[fr][fc];
      if (n0 + 3 < N) {
        const f32x4u bv = *(const f32x4u*)(bias + n0);
        f32x4u o;
#pragma unroll
        for (int q = 0; q < 4; q++) o[q] = v[q] + bv[q];
        __builtin_nontemporal_store(o, (f32x4u*)(C + mRow + n0));
      } else {
#pragma unroll
        for (int q = 0; q < 4; q++)
          if (n0 + q < N) C[mRow + n0 + q] = v[q] + bias[n0 + q];
      }
    }
  }
}

// ---------------------------------------------------------------------------
// MinGRU scan, 3-kernel chunked linear recurrence.
__device__ __forceinline__ void gru_step(float gate, float hid, float& a,
                                         float& g) {
  a = 1.f / (1.f + expf(gate));  // sigmoid(-gate)
  g = (hid >= 0.f) ? (hid + 0.5f) : 1.f / (1.f + expf(-hid));
}

__global__ __launch_bounds__(256) void scan_compose(
    const float* __restrict__ gh, float* __restrict__ Acl,
    float* __restrict__ Vcl) {
  int ck = blockIdx.x;
  int hp = blockIdx.y * 256 + threadIdx.x;
  int b = hp >> 10, h = hp & 1023;
  const float* gb = gh + ((size_t)(b * 2048 + ck * 64)) * 2048 + h;
  float A = 1.f, V = 0.f;
  for (int t = 0; t < 64; t++) {
    float gate = gb[(size_t)t * 2048];
    float hid = gb[(size_t)t * 2048 + 1024];
    float a, g;
    gru_step(gate, hid, a, g);
    V = a * V + (1.f - a) * g;
    A *= a;
  }
  size_t i = (size_t)(b * 32 + ck) * 1024 + h;
  Acl[i] = A;
  Vcl[i] = V;
}

__global__ __launch_bounds__(256) void scan_prefix(
    const float* __restrict__ Acl, const float* __restrict__ Vcl,
    float* __restrict__ Hin) {
  int hp = blockIdx.x * 256 + threadIdx.x;
  int b = hp >> 10, h = hp & 1023;
  float hr = 0.5f;
  for (int ck = 0; ck < 32; ck++) {
    size_t i = (size_t)(b * 32 + ck) * 1024 + h;
    Hin[i] = hr;
    hr = Acl[i] * hr + Vcl[i];
  }
}

__global__ __launch_bounds__(256) void scan_emit(
    const float* __restrict__ gh, const float* __restrict__ Hin,
    const float* __restrict__ res, float* __restrict__ xout) {
  int ck = blockIdx.x;
  int hp = blockIdx.y * 256 + threadIdx.x;
  int b = hp >> 10, h = hp & 1023;
  const float* gb = gh + ((size_t)(b * 2048 + ck * 64)) * 2048 + h;
  const float* rb = res + ((size_t)(b * 2048 + ck * 64)) * 1024 + h;
  float* ob = xout + ((size_t)(b * 2048 + ck * 64)) * 1024 + h;
  float hc = Hin[(size_t)(b * 32 + ck) * 1024 + h];
  for (int t = 0; t < 64; t++) {
    float gate = gb[(size_t)t * 2048];
    float hid = gb[(size_t)t * 2048 + 1024];
    float a, g;
    gru_step(gate, hid, a, g);
    hc = a * hc + (1.f - a) * g;
    ob[(size_t)t * 1024] = hc + rb[(size_t)t * 1024];
  }
}

// ---------------------------------------------------------------------------
extern "C" void kernel_launch(void* const* d_in, const int* in_sizes, int n_in,
                              void* d_out, int out_size, void* d_ws,
                              size_t ws_size, hipStream_t stream) {
  (void)in_sizes; (void)n_in; (void)out_size; (void)ws_size;
  const int* ids = (const int*)d_in[0];
  const float* embW = (const float*)d_in[1];
  const float* ln0w = (const float*)d_in[2];
  const float* ln0b = (const float*)d_in[3];
  const float* g0W = (const float*)d_in[4];
  const float* ln1w = (const float*)d_in[5];
  const float* ln1b = (const float*)d_in[6];
  const float* g1W = (const float*)d_in[7];
  const float* ln2w = (const float*)d_in[8];
  const float* ln2b = (const float*)d_in[9];
  const float* g2W = (const float*)d_in[10];
  const float* r0W = (const float*)d_in[11];
  const float* lnfw = (const float*)d_in[12];
  const float* lnfb = (const float*)d_in[13];
  const float* fcW = (const float*)d_in[14];
  const float* fcb = (const float*)d_in[15];
  float* out = (float*)d_out;

  const int M = 4096;  // B*S
  const int V = 50257;

  // Workspace layout (~191.3 MB total).
  char* ws = (char*)d_ws;
  unsigned short* x_bf = (unsigned short*)(ws + 0);          //  6,291,456
  float* x_f = (float*)(ws + 6291456);                       // 16,777,216
  unsigned short* xn_bf = (unsigned short*)(ws + 23068672);  //  8,388,608
  float* gh = (float*)(ws + 31457280);                       // 33,554,432
  float* r0 = (float*)(ws + 65011712);                       // 16,777,216
  float* Acl = (float*)(ws + 81788928);                      //    262,144
  float* Vcl = (float*)(ws + 82051072);                      //    262,144
  float* Hin = (float*)(ws + 82313216);                      //    262,144
  unsigned short* gwbf = (unsigned short*)(ws + 82575360);   //  4,194,304
  unsigned short* rwbf = (unsigned short*)(ws + 86769664);   //  1,572,864
  unsigned short* fcwbf = (unsigned short*)(ws + 88342528);  // 102,926,336

  auto cvt = [&](const float* src, unsigned short* dst, int n) {
    int n8 = n / 8;
    int grid = min((n8 + 255) / 256, 2048);
    cvt_kernel<<<grid, 256, 0, stream>>>(src, dst, n8);
  };

  embed_kernel<<<M, 256, 0, stream>>>(ids, embW, x_bf);
  cvt(fcW, fcwbf, V * 1024);
  cvt(r0W, rwbf, 1024 * 768);

  // ---- layer 0 (in 768 -> out 1024, residual = x @ res0_W^T) ----
  cvt(g0W, gwbf, 2048 * 768);
  ln_kernel<1, 768><<<M, 256, 0, stream>>>(x_bf, ln0w, ln0b, xn_bf, 1e-5f);
  gemm_bt<<<dim3(16, 32), 256, 0, stream>>>(xn_bf, gwbf, gh, M, 2048, 768);
  gemm_bt<<<dim3(8, 32), 256, 0, stream>>>(x_bf, rwbf, r0, M, 1024, 768);
  scan_compose<<<dim3(32, 8), 256, 0, stream>>>(gh, Acl, Vcl);
  scan_prefix<<<8, 256, 0, stream>>>(Acl, Vcl, Hin);
  scan_emit<<<dim3(32, 8), 256, 0, stream>>>(gh, Hin, r0, x_f);

  // ---- layer 1 (identity residual) ----
  cvt(g1W, gwbf, 2048 * 1024);
  ln_kernel<0, 1024><<<M, 256, 0, stream>>>(x_f, ln1w, ln1b, xn_bf, 1e-5f);
  gemm_bt<<<dim3(16, 32), 256, 0, stream>>>(xn_bf, gwbf, gh, M, 2048, 1024);
  scan_compose<<<dim3(32, 8), 256, 0, stream>>>(gh, Acl, Vcl);
  scan_prefix<<<8, 256, 0, stream>>>(Acl, Vcl, Hin);
  scan_emit<<<dim3(32, 8), 256, 0, stream>>>(gh, Hin, x_f, x_f);

  // ---- layer 2 (identity residual) ----
  cvt(g2W, gwbf, 2048 * 1024);
  ln_kernel<0, 1024><<<M, 256, 0, stream>>>(x_f, ln2w, ln2b, xn_bf, 1e-5f);
  gemm_bt<<<dim3(16, 32), 256, 0, stream>>>(xn_bf, gwbf, gh, M, 2048, 1024);
  scan_compose<<<dim3(32, 8), 256, 0, stream>>>(gh, Acl, Vcl);
  scan_prefix<<<8, 256, 0, stream>>>(Acl, Vcl, Hin);
  scan_emit<<<dim3(32, 8), 256, 0, stream>>>(gh, Hin, x_f, x_f);

  // ---- final LN (eps=0) + vocab GEMM (256^2 8-phase), fp32 out ----
  ln_kernel<0, 1024><<<M, 256, 0, stream>>>(x_f, lnfw, lnfb, xn_bf, 0.0f);
  gemm_bt256<<<dim3(16, (V + 255) / 256), 512, 0, stream>>>(xn_bf, fcwbf, out,
                                                            fcb, M, V, 1024);
}

// Round 10
// 925.799 us; speedup vs baseline: 1.5272x; 1.5272x over previous
//
#include <hip/hip_runtime.h>
#include <stdint.h>
#include <stddef.h>

// ---------------------------------------------------------------------------
// MinGRU NLP model forward on MI355X (gfx950).  ALL float I/O is fp32.
// Pipeline: embed -> [LN -> gates GEMM -> scan(+res)] x3 -> LN -> vocab GEMM.
// Gates GEMMs: proven m97 128x128 BK=32 2-phase structure (round-8 code).
// FINAL vocab GEMM: same 2-phase structure, BK=64 (half the barriers) with
// XOR-swizzled LDS (pre-swizzled global source + swizzled ds_read; zero
// bank conflicts, verified round 9). ROWFAST grid keeps B/A L3-resident
// (round-8 win: FETCH 1.77 GB -> 0.43 GB).
// Epilogue: C staged through LDS -> full 128B-line stores; final GEMM nt.
// Scan: 3-kernel chunked linear recurrence h = a*h + v (32 chunks x 64).
// ---------------------------------------------------------------------------

typedef __attribute__((ext_vector_type(4))) float f32x4;
typedef __attribute__((ext_vector_type(8))) short bf16x8;
typedef float f32x4u __attribute__((vector_size(16), aligned(4)));

__device__ __forceinline__ unsigned short f2bf(float f) {
  unsigned int u = __float_as_uint(f);
  u += 0x7FFFu + ((u >> 16) & 1u);  // RNE
  return (unsigned short)(u >> 16);
}

__device__ __forceinline__ void gload16(const void* g, void* l) {
  __builtin_amdgcn_global_load_lds(
      (const __attribute__((address_space(1))) void*)g,
      (__attribute__((address_space(3))) void*)l, 16, 0, 0);
}

// ---------------------------------------------------------------------------
// fp32 -> bf16 conversion, 8 elems/thread/iter, grid-stride.
__global__ __launch_bounds__(256) void cvt_kernel(
    const float* __restrict__ in, unsigned short* __restrict__ out, int n8) {
  int i = blockIdx.x * 256 + threadIdx.x;
  int stride = gridDim.x * 256;
  for (; i < n8; i += stride) {
    const float4* p = (const float4*)in + (size_t)i * 2;
    float4 a = p[0], b = p[1];
    bf16x8 o;
    o[0] = (short)f2bf(a.x); o[1] = (short)f2bf(a.y);
    o[2] = (short)f2bf(a.z); o[3] = (short)f2bf(a.w);
    o[4] = (short)f2bf(b.x); o[5] = (short)f2bf(b.y);
    o[6] = (short)f2bf(b.z); o[7] = (short)f2bf(b.w);
    *(bf16x8*)(out + (size_t)i * 8) = o;
  }
}

// ---------------------------------------------------------------------------
// Embedding gather + bf16 cast: x_bf[tok, 0:768] = bf16(embW[ids[tok], :])
__global__ __launch_bounds__(256) void embed_kernel(
    const int* __restrict__ ids, const float* __restrict__ embW,
    unsigned short* __restrict__ xbf) {
  int tok = blockIdx.x;
  int id = ids[tok];
  const float* src = embW + (size_t)id * 768;
  unsigned short* dst = xbf + (size_t)tok * 768;
  for (int j = threadIdx.x; j < 768; j += 256) dst[j] = f2bf(src[j]);
}

// ---------------------------------------------------------------------------
// LayerNorm over last dim D, one block per row. Output bf16.
template <int BF16IN, int D>
__global__ __launch_bounds__(256) void ln_kernel(
    const void* __restrict__ xin, const float* __restrict__ w,
    const float* __restrict__ b, unsigned short* __restrict__ xout,
    float eps) {
  constexpr int NV = D / 256;
  int row = blockIdx.x;
  int tid = threadIdx.x;
  int lane = tid & 63, wid = tid >> 6;
  const float* xf = (const float*)xin;
  const unsigned short* xb = (const unsigned short*)xin;
  float vals[NV];
  float s = 0.f, ss = 0.f;
#pragma unroll
  for (int i = 0; i < NV; i++) {
    size_t idx = (size_t)row * D + i * 256 + tid;
    float v;
    if (BF16IN) {
      unsigned int u = ((unsigned int)xb[idx]) << 16;
      v = __uint_as_float(u);
    } else {
      v = xf[idx];
    }
    vals[i] = v;
    s += v;
    ss += v * v;
  }
  for (int off = 32; off; off >>= 1) {
    s += __shfl_down(s, off);
    ss += __shfl_down(ss, off);
  }
  __shared__ float red[8];
  if (lane == 0) { red[wid] = s; red[4 + wid] = ss; }
  __syncthreads();
  s = red[0] + red[1] + red[2] + red[3];
  ss = red[4] + red[5] + red[6] + red[7];
  constexpr float invD = 1.f / (float)D;
  float mu = s * invD;
  float var = ss * invD - mu * mu;
  float inv = rsqrtf(var + eps);
#pragma unroll
  for (int i = 0; i < NV; i++) {
    int col = i * 256 + tid;
    size_t idx = (size_t)row * D + col;
    float y = (vals[i] - mu) * inv * w[col] + b[col];
    xout[idx] = f2bf(y);
  }
}

// ---------------------------------------------------------------------------
// 128x128 BK=32 2-phase GEMM (round-8 proven) for gates/res GEMMs.
// C[M,N] = A[M,K]*B[N,K]^T, fp32 out. Grid dim3(ncb, nrb), x fastest.
__global__ __launch_bounds__(256) void gemm_bt(
    const unsigned short* __restrict__ A, const unsigned short* __restrict__ B,
    float* __restrict__ C, int M, int N, int K) {
  __shared__ __align__(16) char smem[16896];
  unsigned short* lsA = (unsigned short*)smem;
  unsigned short* lsB = (unsigned short*)(smem + 8192);
  float* lsC = (float*)smem;

  const int tid = threadIdx.x;
  const int lane = tid & 63;
  const int wid = __builtin_amdgcn_readfirstlane(tid >> 6);
  const int row0 = blockIdx.y * 128;
  const int col0 = blockIdx.x * 128;

  const int srow = tid >> 2;
  const int skg = (tid & 3) * 8;

  const unsigned short* gA0 = A + (size_t)(row0 + srow) * K + skg;
  const unsigned short* gA1 = A + (size_t)(row0 + 64 + srow) * K + skg;
  const unsigned short* gB0 = B + (size_t)(col0 + srow) * K + skg;
  const unsigned short* gB1 = B + (size_t)(col0 + 64 + srow) * K + skg;

  char* ldsA0 = (char*)lsA + wid * 1024;
  char* ldsA1 = (char*)lsA + 4096 + wid * 1024;
  char* ldsB0 = (char*)lsB + wid * 1024;
  char* ldsB1 = (char*)lsB + 4096 + wid * 1024;

  const int wm = wid >> 1, wn = wid & 1;
  const unsigned short* pA = lsA + (wm * 64 + (lane & 15)) * 32 + (lane >> 4) * 8;
  const unsigned short* pB = lsB + (wn * 64 + (lane & 15)) * 32 + (lane >> 4) * 8;

  f32x4 acc[4][4] = {};

  for (int k0 = 0; k0 < K; k0 += 32) {
    gload16(gA0 + k0, ldsA0);
    gload16(gA1 + k0, ldsA1);
    gload16(gB0 + k0, ldsB0);
    gload16(gB1 + k0, ldsB1);
    __syncthreads();
    bf16x8 af[4], bfr[4];
#pragma unroll
    for (int i = 0; i < 4; i++) af[i] = *(const bf16x8*)(pA + i * 512);
#pragma unroll
    for (int i = 0; i < 4; i++) bfr[i] = *(const bf16x8*)(pB + i * 512);
#pragma unroll
    for (int i = 0; i < 4; i++)
#pragma unroll
      for (int j = 0; j < 4; j++)
        acc[i][j] = __builtin_amdgcn_mfma_f32_16x16x32_bf16(bfr[j], af[i],
                                                            acc[i][j], 0, 0, 0);
    __syncthreads();
  }

  const int mloc = lane & 15;
  const int ng = (lane >> 4) * 4;
  const int LDC = 132;
  const int trow = tid >> 5;
  const int tcol = (tid & 31) * 4;
#pragma unroll
  for (int c = 0; c < 4; c++) {
    if (wm == (c >> 1)) {
      const int i0 = 2 * (c & 1);
#pragma unroll
      for (int ii = 0; ii < 2; ii++)
#pragma unroll
        for (int j = 0; j < 4; j++)
          *(f32x4*)(lsC + (ii * 16 + mloc) * LDC + wn * 64 + j * 16 + ng) =
              acc[i0 + ii][j];
    }
    __syncthreads();
#pragma unroll
    for (int rr = 0; rr < 4; rr++) {
      const int r = rr * 8 + trow;
      const size_t gr = row0 + c * 32 + r;
      f32x4 v = *(const f32x4*)(lsC + r * LDC + tcol);
      *(f32x4*)(C + gr * N + col0 + tcol) = v;
    }
    __syncthreads();
  }
}

// ---------------------------------------------------------------------------
// FINAL vocab GEMM: 128x128 tile, BK=64, 2-phase, XOR-swizzled LDS.
// C[M,N] = A[M,K]*B[N,K]^T + bias, fp32 nt full-line out. ROWFAST grid:
// blockIdx.x = row-block (fastest), blockIdx.y = col-block.
// LDS [128][64] bf16 per matrix (16KB each). Swizzle: LDS slot (row,g)
// holds global granule g^(row&7); staged via pre-swizzled GLOBAL source
// (linear gload_lds dest), read back with the same XOR (rule #21).
__global__ __launch_bounds__(256) void gemm_final64(
    const unsigned short* __restrict__ A, const unsigned short* __restrict__ B,
    float* __restrict__ C, const float* __restrict__ bias, int M, int N,
    int K) {
  __shared__ __align__(16) char smem[32768];
  char* const lsA = smem;            // [128][64] bf16 = 16384 B
  char* const lsB = smem + 16384;
  float* const lsC = (float*)smem;   // epilogue union (16896 B)

  const int t = threadIdx.x;
  const int l = t & 63;
  const int w = __builtin_amdgcn_readfirstlane(t >> 6);
  const int row0 = blockIdx.x * 128;
  const int col0 = blockIdx.y * 128;

  // Staging: per K-step, per matrix: 4 issues x (32 rows x 8 granules).
  // Lane covers row p*32 + (t>>3), LDS granule t&7, global granule
  // (t&7)^((t>>3)&7)  (row&7 key; p*32 == 0 mod 8 so key is issue-invariant).
  const int srow = t >> 3;                     // 0..31
  const int sg = ((t & 7) ^ (srow & 7)) * 8;   // pre-swizzled global elem off
  const unsigned short* gA0 = A + (size_t)(row0 + srow) * K + sg;
  const unsigned short* gA1 = A + (size_t)(row0 + 32 + srow) * K + sg;
  const unsigned short* gA2 = A + (size_t)(row0 + 64 + srow) * K + sg;
  const unsigned short* gA3 = A + (size_t)(row0 + 96 + srow) * K + sg;
  int b0 = min(col0 + srow, N - 1);
  int b1 = min(col0 + 32 + srow, N - 1);
  int b2 = min(col0 + 64 + srow, N - 1);
  int b3 = min(col0 + 96 + srow, N - 1);
  const unsigned short* gB0 = B + (size_t)b0 * K + sg;
  const unsigned short* gB1 = B + (size_t)b1 * K + sg;
  const unsigned short* gB2 = B + (size_t)b2 * K + sg;
  const unsigned short* gB3 = B + (size_t)b3 * K + sg;
  const int wOff = w * 1024;  // wave-uniform LDS chunk within an issue

  // Fragment reads: row r = (wq*64 + (l&15) + i*16), row&7 == l&7.
  const int wm = w >> 1, wn = w & 1;  // 2x2 waves, 64x64 each
  const int aRowB = (wm * 64 + (l & 15)) * 128;
  const int bRowB = (wn * 64 + (l & 15)) * 128;
  const int gk0 = (((l >> 4)) ^ (l & 7)) * 16;      // ks=0 granule (swz)
  const int gk1 = ((4 + (l >> 4)) ^ (l & 7)) * 16;  // ks=1 granule (swz)

  f32x4 acc[4][4] = {};

  for (int k0 = 0; k0 < K; k0 += 64) {
    gload16(gA0 + k0, lsA + wOff);
    gload16(gA1 + k0, lsA + 4096 + wOff);
    gload16(gA2 + k0, lsA + 8192 + wOff);
    gload16(gA3 + k0, lsA + 12288 + wOff);
    gload16(gB0 + k0, lsB + wOff);
    gload16(gB1 + k0, lsB + 4096 + wOff);
    gload16(gB2 + k0, lsB + 8192 + wOff);
    gload16(gB3 + k0, lsB + 12288 + wOff);
    __syncthreads();
    bf16x8 af[4][2], bfr[4][2];
#pragma unroll
    for (int i = 0; i < 4; i++) {
      af[i][0] = *(const bf16x8*)(lsA + aRowB + i * 2048 + gk0);
      af[i][1] = *(const bf16x8*)(lsA + aRowB + i * 2048 + gk1);
    }
#pragma unroll
    for (int j = 0; j < 4; j++) {
      bfr[j][0] = *(const bf16x8*)(lsB + bRowB + j * 2048 + gk0);
      bfr[j][1] = *(const bf16x8*)(lsB + bRowB + j * 2048 + gk1);
    }
#pragma unroll
    for (int i = 0; i < 4; i++)
#pragma unroll
      for (int j = 0; j < 4; j++) {
        acc[i][j] = __builtin_amdgcn_mfma_f32_16x16x32_bf16(
            bfr[j][0], af[i][0], acc[i][j], 0, 0, 0);
        acc[i][j] = __builtin_amdgcn_mfma_f32_16x16x32_bf16(
            bfr[j][1], af[i][1], acc[i][j], 0, 0, 0);
      }
    __syncthreads();
  }

  // ---- Epilogue: LDS transpose -> full-line nt streaming stores ----
  const int mloc = l & 15;
  const int ng = (l >> 4) * 4;
  const int LDC = 132;
  const int trow = t >> 5;
  const int tcol = (t & 31) * 4;
#pragma unroll
  for (int c = 0; c < 4; c++) {
    if (wm == (c >> 1)) {
      const int i0 = 2 * (c & 1);
#pragma unroll
      for (int ii = 0; ii < 2; ii++)
#pragma unroll
        for (int j = 0; j < 4; j++)
          *(f32x4*)(lsC + (ii * 16 + mloc) * LDC + wn * 64 + j * 16 + ng) =
              acc[i0 + ii][j];
    }
    __syncthreads();
#pragma unroll
    for (int rr = 0; rr < 4; rr++) {
      const int r = rr * 8 + trow;
      const size_t gr = row0 + c * 32 + r;
      f32x4 v = *(const f32x4*)(lsC + r * LDC + tcol);
      const int n0 = col0 + tcol;
      if (col0 + 128 <= N) {
        const f32x4u bv = *(const f32x4u*)(bias + n0);
        f32x4u o;
#pragma unroll
        for (int q = 0; q < 4; q++) o[q] = v[q] + bv[q];
        __builtin_nontemporal_store(o, (f32x4u*)(C + gr * N + n0));
      } else {
#pragma unroll
        for (int q = 0; q < 4; q++)
          if (n0 + q < N) C[gr * N + n0 + q] = v[q] + bias[n0 + q];
      }
    }
    __syncthreads();
  }
}

// ---------------------------------------------------------------------------
// MinGRU scan, 3-kernel chunked linear recurrence.
__device__ __forceinline__ void gru_step(float gate, float hid, float& a,
                                         float& g) {
  a = 1.f / (1.f + expf(gate));  // sigmoid(-gate)
  g = (hid >= 0.f) ? (hid + 0.5f) : 1.f / (1.f + expf(-hid));
}

__global__ __launch_bounds__(256) void scan_compose(
    const float* __restrict__ gh, float* __restrict__ Acl,
    float* __restrict__ Vcl) {
  int ck = blockIdx.x;
  int hp = blockIdx.y * 256 + threadIdx.x;
  int b = hp >> 10, h = hp & 1023;
  const float* gb = gh + ((size_t)(b * 2048 + ck * 64)) * 2048 + h;
  float A = 1.f, V = 0.f;
  for (int t = 0; t < 64; t++) {
    float gate = gb[(size_t)t * 2048];
    float hid = gb[(size_t)t * 2048 + 1024];
    float a, g;
    gru_step(gate, hid, a, g);
    V = a * V + (1.f - a) * g;
    A *= a;
  }
  size_t i = (size_t)(b * 32 + ck) * 1024 + h;
  Acl[i] = A;
  Vcl[i] = V;
}

__global__ __launch_bounds__(256) void scan_prefix(
    const float* __restrict__ Acl, const float* __restrict__ Vcl,
    float* __restrict__ Hin) {
  int hp = blockIdx.x * 256 + threadIdx.x;
  int b = hp >> 10, h = hp & 1023;
  float hr = 0.5f;
  for (int ck = 0; ck < 32; ck++) {
    size_t i = (size_t)(b * 32 + ck) * 1024 + h;
    Hin[i] = hr;
    hr = Acl[i] * hr + Vcl[i];
  }
}

__global__ __launch_bounds__(256) void scan_emit(
    const float* __restrict__ gh, const float* __restrict__ Hin,
    const float* __restrict__ res, float* __restrict__ xout) {
  int ck = blockIdx.x;
  int hp = blockIdx.y * 256 + threadIdx.x;
  int b = hp >> 10, h = hp & 1023;
  const float* gb = gh + ((size_t)(b * 2048 + ck * 64)) * 2048 + h;
  const float* rb = res + ((size_t)(b * 2048 + ck * 64)) * 1024 + h;
  float* ob = xout + ((size_t)(b * 2048 + ck * 64)) * 1024 + h;
  float hc = Hin[(size_t)(b * 32 + ck) * 1024 + h];
  for (int t = 0; t < 64; t++) {
    float gate = gb[(size_t)t * 2048];
    float hid = gb[(size_t)t * 2048 + 1024];
    float a, g;
    gru_step(gate, hid, a, g);
    hc = a * hc + (1.f - a) * g;
    ob[(size_t)t * 1024] = hc + rb[(size_t)t * 1024];
  }
}

// ---------------------------------------------------------------------------
extern "C" void kernel_launch(void* const* d_in, const int* in_sizes, int n_in,
                              void* d_out, int out_size, void* d_ws,
                              size_t ws_size, hipStream_t stream) {
  (void)in_sizes; (void)n_in; (void)out_size; (void)ws_size;
  const int* ids = (const int*)d_in[0];
  const float* embW = (const float*)d_in[1];
  const float* ln0w = (const float*)d_in[2];
  const float* ln0b = (const float*)d_in[3];
  const float* g0W = (const float*)d_in[4];
  const float* ln1w = (const float*)d_in[5];
  const float* ln1b = (const float*)d_in[6];
  const float* g1W = (const float*)d_in[7];
  const float* ln2w = (const float*)d_in[8];
  const float* ln2b = (const float*)d_in[9];
  const float* g2W = (const float*)d_in[10];
  const float* r0W = (const float*)d_in[11];
  const float* lnfw = (const float*)d_in[12];
  const float* lnfb = (const float*)d_in[13];
  const float* fcW = (const float*)d_in[14];
  const float* fcb = (const float*)d_in[15];
  float* out = (float*)d_out;

  const int M = 4096;  // B*S
  const int V = 50257;

  // Workspace layout (~191.3 MB total).
  char* ws = (char*)d_ws;
  unsigned short* x_bf = (unsigned short*)(ws + 0);          //  6,291,456
  float* x_f = (float*)(ws + 6291456);                       // 16,777,216
  unsigned short* xn_bf = (unsigned short*)(ws + 23068672);  //  8,388,608
  float* gh = (float*)(ws + 31457280);                       // 33,554,432
  float* r0 = (float*)(ws + 65011712);                       // 16,777,216
  float* Acl = (float*)(ws + 81788928);                      //    262,144
  float* Vcl = (float*)(ws + 82051072);                      //    262,144
  float* Hin = (float*)(ws + 82313216);                      //    262,144
  unsigned short* gwbf = (unsigned short*)(ws + 82575360);   //  4,194,304
  unsigned short* rwbf = (unsigned short*)(ws + 86769664);   //  1,572,864
  unsigned short* fcwbf = (unsigned short*)(ws + 88342528);  // 102,926,336

  auto cvt = [&](const float* src, unsigned short* dst, int n) {
    int n8 = n / 8;
    int grid = min((n8 + 255) / 256, 2048);
    cvt_kernel<<<grid, 256, 0, stream>>>(src, dst, n8);
  };

  embed_kernel<<<M, 256, 0, stream>>>(ids, embW, x_bf);
  cvt(fcW, fcwbf, V * 1024);
  cvt(r0W, rwbf, 1024 * 768);

  // ---- layer 0 (in 768 -> out 1024, residual = x @ res0_W^T) ----
  cvt(g0W, gwbf, 2048 * 768);
  ln_kernel<1, 768><<<M, 256, 0, stream>>>(x_bf, ln0w, ln0b, xn_bf, 1e-5f);
  gemm_bt<<<dim3(16, 32), 256, 0, stream>>>(xn_bf, gwbf, gh, M, 2048, 768);
  gemm_bt<<<dim3(8, 32), 256, 0, stream>>>(x_bf, rwbf, r0, M, 1024, 768);
  scan_compose<<<dim3(32, 8), 256, 0, stream>>>(gh, Acl, Vcl);
  scan_prefix<<<8, 256, 0, stream>>>(Acl, Vcl, Hin);
  scan_emit<<<dim3(32, 8), 256, 0, stream>>>(gh, Hin, r0, x_f);

  // ---- layer 1 (identity residual) ----
  cvt(g1W, gwbf, 2048 * 1024);
  ln_kernel<0, 1024><<<M, 256, 0, stream>>>(x_f, ln1w, ln1b, xn_bf, 1e-5f);
  gemm_bt<<<dim3(16, 32), 256, 0, stream>>>(xn_bf, gwbf, gh, M, 2048, 1024);
  scan_compose<<<dim3(32, 8), 256, 0, stream>>>(gh, Acl, Vcl);
  scan_prefix<<<8, 256, 0, stream>>>(Acl, Vcl, Hin);
  scan_emit<<<dim3(32, 8), 256, 0, stream>>>(gh, Hin, x_f, x_f);

  // ---- layer 2 (identity residual) ----
  cvt(g2W, gwbf, 2048 * 1024);
  ln_kernel<0, 1024><<<M, 256, 0, stream>>>(x_f, ln2w, ln2b, xn_bf, 1e-5f);
  gemm_bt<<<dim3(16, 32), 256, 0, stream>>>(xn_bf, gwbf, gh, M, 2048, 1024);
  scan_compose<<<dim3(32, 8), 256, 0, stream>>>(gh, Acl, Vcl);
  scan_prefix<<<8, 256, 0, stream>>>(Acl, Vcl, Hin);
  scan_emit<<<dim3(32, 8), 256, 0, stream>>>(gh, Hin, x_f, x_f);

  // ---- final LN (eps=0) + vocab GEMM (BK=64, swizzled), fp32 out ----
  // ROWFAST grid: x = 32 row-blocks (fastest), y = 393 col-blocks.
  ln_kernel<0, 1024><<<M, 256, 0, stream>>>(x_f, lnfw, lnfb, xn_bf, 0.0f);
  gemm_final64<<<dim3(32, (V + 127) / 128), 256, 0, stream>>>(
      xn_bf, fcwbf, out, fcb, M, V, 1024);
}

// Round 11
// 900.893 us; speedup vs baseline: 1.5694x; 1.0276x over previous
//
#include <hip/hip_runtime.h>
#include <stdint.h>
#include <stddef.h>

// ---------------------------------------------------------------------------
// MinGRU NLP model forward on MI355X (gfx950).  ALL float I/O is fp32.
// Pipeline: embed -> [LN -> gates GEMM -> scan(+res)] x3 -> LN -> vocab GEMM.
// Gates GEMMs: proven m97 128x128 BK=32 2-phase structure (round-8 code).
// FINAL vocab GEMM: 128x128 BK=64, XOR-swizzled LDS (0 bank conflicts,
// round-10 verified), DOUBLE-BUFFERED with counted vmcnt(8): tile kt+1's
// loads are issued at iteration start and stay in flight across the whole
// compute phase (raw s_barrier; no __syncthreads vmcnt(0) drain in-loop).
// ROWFAST grid keeps B/A L3-resident (round-8: FETCH 1.77 -> 0.43 GB).
// Epilogue: C staged through LDS -> full 128B-line nt stores.
// Scan: 3-kernel chunked linear recurrence h = a*h + v (32 chunks x 64).
// ---------------------------------------------------------------------------

typedef __attribute__((ext_vector_type(4))) float f32x4;
typedef __attribute__((ext_vector_type(8))) short bf16x8;
typedef float f32x4u __attribute__((vector_size(16), aligned(4)));

__device__ __forceinline__ unsigned short f2bf(float f) {
  unsigned int u = __float_as_uint(f);
  u += 0x7FFFu + ((u >> 16) & 1u);  // RNE
  return (unsigned short)(u >> 16);
}

__device__ __forceinline__ void gload16(const void* g, void* l) {
  __builtin_amdgcn_global_load_lds(
      (const __attribute__((address_space(1))) void*)g,
      (__attribute__((address_space(3))) void*)l, 16, 0, 0);
}

#define MEMFENCE asm volatile("" ::: "memory")

// ---------------------------------------------------------------------------
// fp32 -> bf16 conversion, 8 elems/thread/iter, grid-stride.
__global__ __launch_bounds__(256) void cvt_kernel(
    const float* __restrict__ in, unsigned short* __restrict__ out, int n8) {
  int i = blockIdx.x * 256 + threadIdx.x;
  int stride = gridDim.x * 256;
  for (; i < n8; i += stride) {
    const float4* p = (const float4*)in + (size_t)i * 2;
    float4 a = p[0], b = p[1];
    bf16x8 o;
    o[0] = (short)f2bf(a.x); o[1] = (short)f2bf(a.y);
    o[2] = (short)f2bf(a.z); o[3] = (short)f2bf(a.w);
    o[4] = (short)f2bf(b.x); o[5] = (short)f2bf(b.y);
    o[6] = (short)f2bf(b.z); o[7] = (short)f2bf(b.w);
    *(bf16x8*)(out + (size_t)i * 8) = o;
  }
}

// ---------------------------------------------------------------------------
// Embedding gather + bf16 cast: x_bf[tok, 0:768] = bf16(embW[ids[tok], :])
__global__ __launch_bounds__(256) void embed_kernel(
    const int* __restrict__ ids, const float* __restrict__ embW,
    unsigned short* __restrict__ xbf) {
  int tok = blockIdx.x;
  int id = ids[tok];
  const float* src = embW + (size_t)id * 768;
  unsigned short* dst = xbf + (size_t)tok * 768;
  for (int j = threadIdx.x; j < 768; j += 256) dst[j] = f2bf(src[j]);
}

// ---------------------------------------------------------------------------
// LayerNorm over last dim D, one block per row. Output bf16.
template <int BF16IN, int D>
__global__ __launch_bounds__(256) void ln_kernel(
    const void* __restrict__ xin, const float* __restrict__ w,
    const float* __restrict__ b, unsigned short* __restrict__ xout,
    float eps) {
  constexpr int NV = D / 256;
  int row = blockIdx.x;
  int tid = threadIdx.x;
  int lane = tid & 63, wid = tid >> 6;
  const float* xf = (const float*)xin;
  const unsigned short* xb = (const unsigned short*)xin;
  float vals[NV];
  float s = 0.f, ss = 0.f;
#pragma unroll
  for (int i = 0; i < NV; i++) {
    size_t idx = (size_t)row * D + i * 256 + tid;
    float v;
    if (BF16IN) {
      unsigned int u = ((unsigned int)xb[idx]) << 16;
      v = __uint_as_float(u);
    } else {
      v = xf[idx];
    }
    vals[i] = v;
    s += v;
    ss += v * v;
  }
  for (int off = 32; off; off >>= 1) {
    s += __shfl_down(s, off);
    ss += __shfl_down(ss, off);
  }
  __shared__ float red[8];
  if (lane == 0) { red[wid] = s; red[4 + wid] = ss; }
  __syncthreads();
  s = red[0] + red[1] + red[2] + red[3];
  ss = red[4] + red[5] + red[6] + red[7];
  constexpr float invD = 1.f / (float)D;
  float mu = s * invD;
  float var = ss * invD - mu * mu;
  float inv = rsqrtf(var + eps);
#pragma unroll
  for (int i = 0; i < NV; i++) {
    int col = i * 256 + tid;
    size_t idx = (size_t)row * D + col;
    float y = (vals[i] - mu) * inv * w[col] + b[col];
    xout[idx] = f2bf(y);
  }
}

// ---------------------------------------------------------------------------
// 128x128 BK=32 2-phase GEMM (round-8 proven) for gates/res GEMMs.
// C[M,N] = A[M,K]*B[N,K]^T, fp32 out. Grid dim3(ncb, nrb), x fastest.
__global__ __launch_bounds__(256) void gemm_bt(
    const unsigned short* __restrict__ A, const unsigned short* __restrict__ B,
    float* __restrict__ C, int M, int N, int K) {
  __shared__ __align__(16) char smem[16896];
  unsigned short* lsA = (unsigned short*)smem;
  unsigned short* lsB = (unsigned short*)(smem + 8192);
  float* lsC = (float*)smem;

  const int tid = threadIdx.x;
  const int lane = tid & 63;
  const int wid = __builtin_amdgcn_readfirstlane(tid >> 6);
  const int row0 = blockIdx.y * 128;
  const int col0 = blockIdx.x * 128;

  const int srow = tid >> 2;
  const int skg = (tid & 3) * 8;

  const unsigned short* gA0 = A + (size_t)(row0 + srow) * K + skg;
  const unsigned short* gA1 = A + (size_t)(row0 + 64 + srow) * K + skg;
  const unsigned short* gB0 = B + (size_t)(col0 + srow) * K + skg;
  const unsigned short* gB1 = B + (size_t)(col0 + 64 + srow) * K + skg;

  char* ldsA0 = (char*)lsA + wid * 1024;
  char* ldsA1 = (char*)lsA + 4096 + wid * 1024;
  char* ldsB0 = (char*)lsB + wid * 1024;
  char* ldsB1 = (char*)lsB + 4096 + wid * 1024;

  const int wm = wid >> 1, wn = wid & 1;
  const unsigned short* pA = lsA + (wm * 64 + (lane & 15)) * 32 + (lane >> 4) * 8;
  const unsigned short* pB = lsB + (wn * 64 + (lane & 15)) * 32 + (lane >> 4) * 8;

  f32x4 acc[4][4] = {};

  for (int k0 = 0; k0 < K; k0 += 32) {
    gload16(gA0 + k0, ldsA0);
    gload16(gA1 + k0, ldsA1);
    gload16(gB0 + k0, ldsB0);
    gload16(gB1 + k0, ldsB1);
    __syncthreads();
    bf16x8 af[4], bfr[4];
#pragma unroll
    for (int i = 0; i < 4; i++) af[i] = *(const bf16x8*)(pA + i * 512);
#pragma unroll
    for (int i = 0; i < 4; i++) bfr[i] = *(const bf16x8*)(pB + i * 512);
#pragma unroll
    for (int i = 0; i < 4; i++)
#pragma unroll
      for (int j = 0; j < 4; j++)
        acc[i][j] = __builtin_amdgcn_mfma_f32_16x16x32_bf16(bfr[j], af[i],
                                                            acc[i][j], 0, 0, 0);
    __syncthreads();
  }

  const int mloc = lane & 15;
  const int ng = (lane >> 4) * 4;
  const int LDC = 132;
  const int trow = tid >> 5;
  const int tcol = (tid & 31) * 4;
#pragma unroll
  for (int c = 0; c < 4; c++) {
    if (wm == (c >> 1)) {
      const int i0 = 2 * (c & 1);
#pragma unroll
      for (int ii = 0; ii < 2; ii++)
#pragma unroll
        for (int j = 0; j < 4; j++)
          *(f32x4*)(lsC + (ii * 16 + mloc) * LDC + wn * 64 + j * 16 + ng) =
              acc[i0 + ii][j];
    }
    __syncthreads();
#pragma unroll
    for (int rr = 0; rr < 4; rr++) {
      const int r = rr * 8 + trow;
      const size_t gr = row0 + c * 32 + r;
      f32x4 v = *(const f32x4*)(lsC + r * LDC + tcol);
      *(f32x4*)(C + gr * N + col0 + tcol) = v;
    }
    __syncthreads();
  }
}

// ---------------------------------------------------------------------------
// FINAL vocab GEMM: 128x128, BK=64, XOR-swizzled LDS, DOUBLE-BUFFERED with
// counted vmcnt(8). C[M,N] = A[M,K]*B[N,K]^T + bias, fp32 nt full-line out.
// ROWFAST grid: blockIdx.x = row-block (fastest), blockIdx.y = col-block.
// LDS: 2 bufs x ([128][64] A + [128][64] B) = 64 KiB; epilogue unions lsC.
// Per iteration kt: issue tile kt+1 loads into buf^1, vmcnt(8) waits ONLY
// tile kt's loads (kt+1's 8 stay in flight across compute), raw s_barrier.
__global__ __launch_bounds__(256) void gemm_final64(
    const unsigned short* __restrict__ A, const unsigned short* __restrict__ B,
    float* __restrict__ C, const float* __restrict__ bias, int M, int N,
    int K) {
  __shared__ __align__(16) char smem[65536];
  float* const lsC = (float*)smem;  // epilogue union (16896 B)

  const int t = threadIdx.x;
  const int l = t & 63;
  const int w = __builtin_amdgcn_readfirstlane(t >> 6);
  const int row0 = blockIdx.x * 128;
  const int col0 = blockIdx.y * 128;

  // Staging: per tile, per matrix: 4 issues x (32 rows x 8 granules).
  const int srow = t >> 3;                     // 0..31
  const int sg = ((t & 7) ^ (srow & 7)) * 8;   // pre-swizzled global elem off
  const unsigned short* gA0 = A + (size_t)(row0 + srow) * K + sg;
  const unsigned short* gA1 = A + (size_t)(row0 + 32 + srow) * K + sg;
  const unsigned short* gA2 = A + (size_t)(row0 + 64 + srow) * K + sg;
  const unsigned short* gA3 = A + (size_t)(row0 + 96 + srow) * K + sg;
  int b0 = min(col0 + srow, N - 1);
  int b1 = min(col0 + 32 + srow, N - 1);
  int b2 = min(col0 + 64 + srow, N - 1);
  int b3 = min(col0 + 96 + srow, N - 1);
  const unsigned short* gB0 = B + (size_t)b0 * K + sg;
  const unsigned short* gB1 = B + (size_t)b1 * K + sg;
  const unsigned short* gB2 = B + (size_t)b2 * K + sg;
  const unsigned short* gB3 = B + (size_t)b3 * K + sg;
  const int wOff = w * 1024;  // wave-uniform LDS chunk within an issue

  // Fragment reads: row r = (wq*64 + (l&15) + i*16), row&7 == l&7.
  const int wm = w >> 1, wn = w & 1;  // 2x2 waves, 64x64 each
  const int aRowB = (wm * 64 + (l & 15)) * 128;
  const int bRowB = (wn * 64 + (l & 15)) * 128;
  const int gk0 = (((l >> 4)) ^ (l & 7)) * 16;      // ks=0 granule (swz)
  const int gk1 = ((4 + (l >> 4)) ^ (l & 7)) * 16;  // ks=1 granule (swz)

  f32x4 acc[4][4] = {};

#define STAGE(BUF, KOFF)                            \
  do {                                              \
    char* a_ = smem + (BUF) * 32768;                \
    char* b_ = a_ + 16384;                          \
    gload16(gA0 + (KOFF), a_ + wOff);               \
    gload16(gA1 + (KOFF), a_ + 4096 + wOff);        \
    gload16(gA2 + (KOFF), a_ + 8192 + wOff);        \
    gload16(gA3 + (KOFF), a_ + 12288 + wOff);       \
    gload16(gB0 + (KOFF), b_ + wOff);               \
    gload16(gB1 + (KOFF), b_ + 4096 + wOff);        \
    gload16(gB2 + (KOFF), b_ + 8192 + wOff);        \
    gload16(gB3 + (KOFF), b_ + 12288 + wOff);       \
  } while (0)

  // Prologue: stage tile 0 into buf 0.
  STAGE(0, 0);

  const int NK = K >> 6;
  for (int kt = 0; kt < NK; ++kt) {
    const int cur = kt & 1;
    const char* aB = smem + cur * 32768;
    const char* bB = aB + 16384;

    if (kt + 1 < NK) {
      STAGE(cur ^ 1, (kt + 1) << 6);  // buf^1 free: prev iter's trailing bar
      asm volatile("s_waitcnt vmcnt(8)" ::: "memory");  // tile kt landed
    } else {
      asm volatile("s_waitcnt vmcnt(0)" ::: "memory");
    }
    __builtin_amdgcn_s_barrier();
    MEMFENCE;

    bf16x8 af[4][2], bfr[4][2];
#pragma unroll
    for (int i = 0; i < 4; i++) {
      af[i][0] = *(const bf16x8*)(aB + aRowB + i * 2048 + gk0);
      af[i][1] = *(const bf16x8*)(aB + aRowB + i * 2048 + gk1);
    }
#pragma unroll
    for (int j = 0; j < 4; j++) {
      bfr[j][0] = *(const bf16x8*)(bB + bRowB + j * 2048 + gk0);
      bfr[j][1] = *(const bf16x8*)(bB + bRowB + j * 2048 + gk1);
    }
#pragma unroll
    for (int i = 0; i < 4; i++)
#pragma unroll
      for (int j = 0; j < 4; j++) {
        acc[i][j] = __builtin_amdgcn_mfma_f32_16x16x32_bf16(
            bfr[j][0], af[i][0], acc[i][j], 0, 0, 0);
        acc[i][j] = __builtin_amdgcn_mfma_f32_16x16x32_bf16(
            bfr[j][1], af[i][1], acc[i][j], 0, 0, 0);
      }

    MEMFENCE;
    __builtin_amdgcn_s_barrier();  // all reads of buf[cur] done before reuse
    MEMFENCE;
  }
#undef STAGE

  // ---- Epilogue: LDS transpose -> full-line nt streaming stores ----
  const int mloc = l & 15;
  const int ng = (l >> 4) * 4;
  const int LDC = 132;
  const int trow = t >> 5;
  const int tcol = (t & 31) * 4;
#pragma unroll
  for (int c = 0; c < 4; c++) {
    if (wm == (c >> 1)) {
      const int i0 = 2 * (c & 1);
#pragma unroll
      for (int ii = 0; ii < 2; ii++)
#pragma unroll
        for (int j = 0; j < 4; j++)
          *(f32x4*)(lsC + (ii * 16 + mloc) * LDC + wn * 64 + j * 16 + ng) =
              acc[i0 + ii][j];
    }
    __syncthreads();
#pragma unroll
    for (int rr = 0; rr < 4; rr++) {
      const int r = rr * 8 + trow;
      const size_t gr = row0 + c * 32 + r;
      f32x4 v = *(const f32x4*)(lsC + r * LDC + tcol);
      const int n0 = col0 + tcol;
      if (col0 + 128 <= N) {
        const f32x4u bv = *(const f32x4u*)(bias + n0);
        f32x4u o;
#pragma unroll
        for (int q = 0; q < 4; q++) o[q] = v[q] + bv[q];
        __builtin_nontemporal_store(o, (f32x4u*)(C + gr * N + n0));
      } else {
#pragma unroll
        for (int q = 0; q < 4; q++)
          if (n0 + q < N) C[gr * N + n0 + q] = v[q] + bias[n0 + q];
      }
    }
    __syncthreads();
  }
}

// ---------------------------------------------------------------------------
// MinGRU scan, 3-kernel chunked linear recurrence.
__device__ __forceinline__ void gru_step(float gate, float hid, float& a,
                                         float& g) {
  a = 1.f / (1.f + expf(gate));  // sigmoid(-gate)
  g = (hid >= 0.f) ? (hid + 0.5f) : 1.f / (1.f + expf(-hid));
}

__global__ __launch_bounds__(256) void scan_compose(
    const float* __restrict__ gh, float* __restrict__ Acl,
    float* __restrict__ Vcl) {
  int ck = blockIdx.x;
  int hp = blockIdx.y * 256 + threadIdx.x;
  int b = hp >> 10, h = hp & 1023;
  const float* gb = gh + ((size_t)(b * 2048 + ck * 64)) * 2048 + h;
  float A = 1.f, V = 0.f;
  for (int t = 0; t < 64; t++) {
    float gate = gb[(size_t)t * 2048];
    float hid = gb[(size_t)t * 2048 + 1024];
    float a, g;
    gru_step(gate, hid, a, g);
    V = a * V + (1.f - a) * g;
    A *= a;
  }
  size_t i = (size_t)(b * 32 + ck) * 1024 + h;
  Acl[i] = A;
  Vcl[i] = V;
}

__global__ __launch_bounds__(256) void scan_prefix(
    const float* __restrict__ Acl, const float* __restrict__ Vcl,
    float* __restrict__ Hin) {
  int hp = blockIdx.x * 256 + threadIdx.x;
  int b = hp >> 10, h = hp & 1023;
  float hr = 0.5f;
  for (int ck = 0; ck < 32; ck++) {
    size_t i = (size_t)(b * 32 + ck) * 1024 + h;
    Hin[i] = hr;
    hr = Acl[i] * hr + Vcl[i];
  }
}

__global__ __launch_bounds__(256) void scan_emit(
    const float* __restrict__ gh, const float* __restrict__ Hin,
    const float* __restrict__ res, float* __restrict__ xout) {
  int ck = blockIdx.x;
  int hp = blockIdx.y * 256 + threadIdx.x;
  int b = hp >> 10, h = hp & 1023;
  const float* gb = gh + ((size_t)(b * 2048 + ck * 64)) * 2048 + h;
  const float* rb = res + ((size_t)(b * 2048 + ck * 64)) * 1024 + h;
  float* ob = xout + ((size_t)(b * 2048 + ck * 64)) * 1024 + h;
  float hc = Hin[(size_t)(b * 32 + ck) * 1024 + h];
  for (int t = 0; t < 64; t++) {
    float gate = gb[(size_t)t * 2048];
    float hid = gb[(size_t)t * 2048 + 1024];
    float a, g;
    gru_step(gate, hid, a, g);
    hc = a * hc + (1.f - a) * g;
    ob[(size_t)t * 1024] = hc + rb[(size_t)t * 1024];
  }
}

// ---------------------------------------------------------------------------
extern "C" void kernel_launch(void* const* d_in, const int* in_sizes, int n_in,
                              void* d_out, int out_size, void* d_ws,
                              size_t ws_size, hipStream_t stream) {
  (void)in_sizes; (void)n_in; (void)out_size; (void)ws_size;
  const int* ids = (const int*)d_in[0];
  const float* embW = (const float*)d_in[1];
  const float* ln0w = (const float*)d_in[2];
  const float* ln0b = (const float*)d_in[3];
  const float* g0W = (const float*)d_in[4];
  const float* ln1w = (const float*)d_in[5];
  const float* ln1b = (const float*)d_in[6];
  const float* g1W = (const float*)d_in[7];
  const float* ln2w = (const float*)d_in[8];
  const float* ln2b = (const float*)d_in[9];
  const float* g2W = (const float*)d_in[10];
  const float* r0W = (const float*)d_in[11];
  const float* lnfw = (const float*)d_in[12];
  const float* lnfb = (const float*)d_in[13];
  const float* fcW = (const float*)d_in[14];
  const float* fcb = (const float*)d_in[15];
  float* out = (float*)d_out;

  const int M = 4096;  // B*S
  const int V = 50257;

  // Workspace layout (~191.3 MB total).
  char* ws = (char*)d_ws;
  unsigned short* x_bf = (unsigned short*)(ws + 0);          //  6,291,456
  float* x_f = (float*)(ws + 6291456);                       // 16,777,216
  unsigned short* xn_bf = (unsigned short*)(ws + 23068672);  //  8,388,608
  float* gh = (float*)(ws + 31457280);                       // 33,554,432
  float* r0 = (float*)(ws + 65011712);                       // 16,777,216
  float* Acl = (float*)(ws + 81788928);                      //    262,144
  float* Vcl = (float*)(ws + 82051072);                      //    262,144
  float* Hin = (float*)(ws + 82313216);                      //    262,144
  unsigned short* gwbf = (unsigned short*)(ws + 82575360);   //  4,194,304
  unsigned short* rwbf = (unsigned short*)(ws + 86769664);   //  1,572,864
  unsigned short* fcwbf = (unsigned short*)(ws + 88342528);  // 102,926,336

  auto cvt = [&](const float* src, unsigned short* dst, int n) {
    int n8 = n / 8;
    int grid = min((n8 + 255) / 256, 2048);
    cvt_kernel<<<grid, 256, 0, stream>>>(src, dst, n8);
  };

  embed_kernel<<<M, 256, 0, stream>>>(ids, embW, x_bf);
  cvt(fcW, fcwbf, V * 1024);
  cvt(r0W, rwbf, 1024 * 768);

  // ---- layer 0 (in 768 -> out 1024, residual = x @ res0_W^T) ----
  cvt(g0W, gwbf, 2048 * 768);
  ln_kernel<1, 768><<<M, 256, 0, stream>>>(x_bf, ln0w, ln0b, xn_bf, 1e-5f);
  gemm_bt<<<dim3(16, 32), 256, 0, stream>>>(xn_bf, gwbf, gh, M, 2048, 768);
  gemm_bt<<<dim3(8, 32), 256, 0, stream>>>(x_bf, rwbf, r0, M, 1024, 768);
  scan_compose<<<dim3(32, 8), 256, 0, stream>>>(gh, Acl, Vcl);
  scan_prefix<<<8, 256, 0, stream>>>(Acl, Vcl, Hin);
  scan_emit<<<dim3(32, 8), 256, 0, stream>>>(gh, Hin, r0, x_f);

  // ---- layer 1 (identity residual) ----
  cvt(g1W, gwbf, 2048 * 1024);
  ln_kernel<0, 1024><<<M, 256, 0, stream>>>(x_f, ln1w, ln1b, xn_bf, 1e-5f);
  gemm_bt<<<dim3(16, 32), 256, 0, stream>>>(xn_bf, gwbf, gh, M, 2048, 1024);
  scan_compose<<<dim3(32, 8), 256, 0, stream>>>(gh, Acl, Vcl);
  scan_prefix<<<8, 256, 0, stream>>>(Acl, Vcl, Hin);
  scan_emit<<<dim3(32, 8), 256, 0, stream>>>(gh, Hin, x_f, x_f);

  // ---- layer 2 (identity residual) ----
  cvt(g2W, gwbf, 2048 * 1024);
  ln_kernel<0, 1024><<<M, 256, 0, stream>>>(x_f, ln2w, ln2b, xn_bf, 1e-5f);
  gemm_bt<<<dim3(16, 32), 256, 0, stream>>>(xn_bf, gwbf, gh, M, 2048, 1024);
  scan_compose<<<dim3(32, 8), 256, 0, stream>>>(gh, Acl, Vcl);
  scan_prefix<<<8, 256, 0, stream>>>(Acl, Vcl, Hin);
  scan_emit<<<dim3(32, 8), 256, 0, stream>>>(gh, Hin, x_f, x_f);

  // ---- final LN (eps=0) + vocab GEMM (BK=64, swz, dbuf+vmcnt(8)) ----
  // ROWFAST grid: x = 32 row-blocks (fastest), y = 393 col-blocks.
  ln_kernel<0, 1024><<<M, 256, 0, stream>>>(x_f, lnfw, lnfb, xn_bf, 0.0f);
  gemm_final64<<<dim3(32, (V + 127) / 128), 256, 0, stream>>>(
      xn_bf, fcwbf, out, fcb, M, V, 1024);
}